// Round 8
// baseline (303.257 us; speedup 1.0000x reference)
//
#include <hip/hip_runtime.h>

// Clustering attention for MI355X.
// ws float-offsets (round-1-proven 4.2 MB footprint)
#define KS_OFF 0
#define VS_OFF 262144
#define QM_OFF 524288
#define AM_OFF 786432
#define LP_OFF 1048576
#define CE_OFF 1048832

typedef __attribute__((ext_vector_type(8))) short short8;
typedef __attribute__((ext_vector_type(4))) float f32x4;

__device__ inline unsigned short bfb(float x) {
  unsigned u = __float_as_uint(x);
  return (unsigned short)((u + 0x7fffu + ((u >> 16) & 1u)) >> 16);
}
__device__ inline unsigned pk2(float a, float b) {
  return (unsigned)bfb(a) | ((unsigned)bfb(b) << 16);
}
__device__ inline float bft(unsigned short h) {
  return __uint_as_float((unsigned)h << 16);
}
// 3-way split: x = bft(h)+bft(m)+bft(l) + eps, |eps| <= ~2^-25 |x|.
__device__ inline void split3(float x, unsigned short& h, unsigned short& m, unsigned short& l) {
  unsigned u = __float_as_uint(x);
  h = (unsigned short)(u >> 16);
  float r = x - bft(h);
  m = (unsigned short)(__float_as_uint(r) >> 16);
  float r2 = r - bft(m);
  l = bfb(r2);
}
__device__ inline void gload16(const void* g, void* l) {
  __builtin_amdgcn_global_load_lds(
      (const __attribute__((address_space(1))) unsigned*)g,
      (__attribute__((address_space(3))) unsigned*)l, 16, 0, 0);
}

// ---------------- Kernel 1a: shrink partials, DMA double-buffered pipeline ----------------
// grid 2048 = (tensor,bh,quarter), block 256 (4 waves). At the empirical ~3.5 TB/s
// read-path ceiling (537 MB unique reads / ~155 us) — kept as-is.
__global__ __launch_bounds__(256) void k_shrink6(
    const float* __restrict__ K, const float* __restrict__ V,
    const float* __restrict__ skw, const float* __restrict__ svw,
    float* __restrict__ part)
{
  int blk = blockIdx.x;
  int q = blk & 3;
  int bh = (blk >> 2) & 255;
  int tensor = blk >> 10;      // 0 = K, 1 = V
  const float* __restrict__ src = (tensor ? V : K) + (size_t)bh * (4096 * 64);
  const float* __restrict__ w   = tensor ? svw : skw;
  float* __restrict__ dst = part + (size_t)blk * 1024;

  int t = threadIdx.x;
  int wv = t >> 6;
  int l = t & 63;
  int l15 = l & 15;
  int kg = l >> 4;             // 0..3
  int lr4 = l >> 4;            // row-in-chunk for staging
  union Frag { unsigned u[4]; short8 s8; };

  __shared__ float shm[16384];  // two 32 KB buffers [buf][128][64]

#define STAGE(buf, sub) do {                                                  \
    const float* gs = src + (size_t)(q * 1024 + (sub) * 128) * 64;            \
    _Pragma("unroll")                                                         \
    for (int i = 0; i < 8; ++i) {                                             \
      int ch = wv * 8 + i;                                                    \
      int row = ch * 4 + lr4;                                                 \
      int s16 = (l & 15) ^ (((row >> 3) & 3) << 2);                           \
      gload16(gs + (size_t)row * 64 + s16 * 4, &shm[(buf) * 8192 + ch * 256]);\
    } } while (0)

  f32x4 acc[4];
#pragma unroll
  for (int nt = 0; nt < 4; ++nt) acc[nt] = (f32x4){0.f, 0.f, 0.f, 0.f};

  const float* __restrict__ wrow = w + l15 * 4096 + kg * 8;

  STAGE(0, 0);
  int kk0 = q * 32 + wv;
  float4 wa_c = *(const float4*)(wrow + kk0 * 32);
  float4 wb_c = *(const float4*)(wrow + kk0 * 32 + 4);
  __syncthreads();

  for (int sub = 0; sub < 8; ++sub) {
    int cur = sub & 1;
    if (sub < 7) STAGE(cur ^ 1, sub + 1);
    float4 wa_n, wb_n;
    if (sub < 7) {
      int kkn = q * 32 + (sub + 1) * 4 + wv;
      wa_n = *(const float4*)(wrow + kkn * 32);
      wb_n = *(const float4*)(wrow + kkn * 32 + 4);
    }

    float we[8] = {wa_c.x, wa_c.y, wa_c.z, wa_c.w, wb_c.x, wb_c.y, wb_c.z, wb_c.w};
    Frag ah, am, al;
#pragma unroll
    for (int e = 0; e < 4; ++e) {
      unsigned short h0, m0, l0, h1, m1, l1;
      split3(we[2 * e], h0, m0, l0);
      split3(we[2 * e + 1], h1, m1, l1);
      ah.u[e] = (unsigned)h0 | ((unsigned)h1 << 16);
      am.u[e] = (unsigned)m0 | ((unsigned)m1 << 16);
      al.u[e] = (unsigned)l0 | ((unsigned)l1 << 16);
    }

    const float* __restrict__ stage = &shm[cur * 8192];
#pragma unroll
    for (int nt = 0; nt < 4; ++nt) {
      float v[8];
#pragma unroll
      for (int j = 0; j < 8; ++j) {
        int row = wv * 32 + kg * 8 + j;
        int col = (nt * 16 + l15) ^ (((row >> 3) & 3) << 4);
        v[j] = stage[row * 64 + col];
      }
      Frag bh, bm, bl;
#pragma unroll
      for (int e = 0; e < 4; ++e) {
        unsigned short h0, m0, l0, h1, m1, l1;
        split3(v[2 * e], h0, m0, l0);
        split3(v[2 * e + 1], h1, m1, l1);
        bh.u[e] = (unsigned)h0 | ((unsigned)h1 << 16);
        bm.u[e] = (unsigned)m0 | ((unsigned)m1 << 16);
        bl.u[e] = (unsigned)l0 | ((unsigned)l1 << 16);
      }
      acc[nt] = __builtin_amdgcn_mfma_f32_16x16x32_bf16(ah.s8, bh.s8, acc[nt], 0, 0, 0);
      acc[nt] = __builtin_amdgcn_mfma_f32_16x16x32_bf16(ah.s8, bm.s8, acc[nt], 0, 0, 0);
      acc[nt] = __builtin_amdgcn_mfma_f32_16x16x32_bf16(am.s8, bh.s8, acc[nt], 0, 0, 0);
      acc[nt] = __builtin_amdgcn_mfma_f32_16x16x32_bf16(ah.s8, bl.s8, acc[nt], 0, 0, 0);
      acc[nt] = __builtin_amdgcn_mfma_f32_16x16x32_bf16(al.s8, bh.s8, acc[nt], 0, 0, 0);
      acc[nt] = __builtin_amdgcn_mfma_f32_16x16x32_bf16(am.s8, bm.s8, acc[nt], 0, 0, 0);
    }

    if (sub < 7) { wa_c = wa_n; wb_c = wb_n; }
    __syncthreads();
  }

  int g4 = kg * 4;
#pragma unroll
  for (int nt = 0; nt < 4; ++nt)
#pragma unroll
    for (int r = 0; r < 4; ++r)
      shm[wv * 1024 + (g4 + r) * 64 + nt * 16 + l15] = acc[nt][r];
  __syncthreads();
  for (int p = t; p < 1024; p += 256)
    dst[p] = shm[p] + shm[1024 + p] + shm[2048 + p] + shm[3072 + p];
#undef STAGE
}

// ---------------- Kernel 1b: reduce 4 quarter-partials + bias -> ws ----------------
__global__ __launch_bounds__(256) void k_shrink_red(
    const float* __restrict__ part, const float* __restrict__ skb,
    const float* __restrict__ svb, float* __restrict__ ws)
{
  int blk = blockIdx.x;        // 512 = (tensor,bh)
  int tensor = blk >> 8;
  int bh = blk & 255;
  const float* __restrict__ p0 = part + ((size_t)(tensor * 1024 + bh * 4)) * 1024;
  const float* __restrict__ bias = tensor ? svb : skb;
  float* __restrict__ dst = ws + (tensor ? VS_OFF : KS_OFF) + bh * 1024;
  for (int p = threadIdx.x; p < 1024; p += 256)
    dst[p] = ((p0[p] + p0[1024 + p]) + (p0[2048 + p] + p0[3072 + p])) + bias[p >> 6];
}

// ---------------- Kernel 2: cluster nets + loss partials + (q_mean, argmax) ----------------
// grid 256 = (b,s), block 1024 = (h,d). LDS holds cq for the h-axis log_softmax.
__global__ __launch_bounds__(1024) void k_cluster(
    const float* __restrict__ pw, const float* __restrict__ pb,
    const float* __restrict__ ckw, const float* __restrict__ ckb,
    const float* __restrict__ cqw, const float* __restrict__ cqb,
    const float* __restrict__ muw, const float* __restrict__ mub,
    const float* __restrict__ sgw, const float* __restrict__ sgb,
    float* __restrict__ ws)
{
  int bidx = blockIdx.x >> 4;   // batch index i of the unfold
  int sIdx = blockIdx.x & 15;
  int t = threadIdx.x;
  int h = t >> 6, d = t & 63;

  __shared__ float wgt[610];    // pw160|pb10|ckw100|ckb10|cqw100|cqb10|muw100|mub10|sgw100|sgb10
  __shared__ float cqs[16 * 64 * 10];
  if (t < 160) wgt[t] = pw[t];
  else if (t < 170) wgt[t] = pb[t - 160];
  else if (t < 270) wgt[t] = ckw[t - 170];
  else if (t < 280) wgt[t] = ckb[t - 270];
  else if (t < 380) wgt[t] = cqw[t - 280];
  else if (t < 390) wgt[t] = cqb[t - 380];
  else if (t < 490) wgt[t] = muw[t - 390];
  else if (t < 500) wgt[t] = mub[t - 490];
  else if (t < 600) wgt[t] = sgw[t - 500];
  else if (t < 610) wgt[t] = sgb[t - 600];
  __syncthreads();

  const float* __restrict__ Ks = ws + KS_OFF;

  // K_unfold[i,h,s,d,j] = (i+j<16) ? 0 : Ks[i+j-15]; proj over j => sum_{m=1..i} Ks[m]*pw[c][m+15-i]
  float ckp[10];
#pragma unroll
  for (int c = 0; c < 10; ++c) ckp[c] = wgt[160 + c];
  for (int m = 1; m <= bidx; ++m) {
    float kv = Ks[((m * 16 + h) * 16 + sIdx) * 64 + d];
    int j = m + 15 - bidx;
#pragma unroll
    for (int c = 0; c < 10; ++c) ckp[c] = fmaf(kv, wgt[c * 16 + j], ckp[c]);
  }
#pragma unroll
  for (int c = 0; c < 10; ++c) ckp[c] = fmaxf(ckp[c], 0.f);

  float zk[10], zq[10];
#pragma unroll
  for (int c = 0; c < 10; ++c) { zk[c] = wgt[270 + c]; zq[c] = wgt[380 + c]; }
#pragma unroll
  for (int j = 0; j < 10; ++j) {
    float v = ckp[j];
#pragma unroll
    for (int c = 0; c < 10; ++c) {
      zk[c] = fmaf(v, wgt[170 + c * 10 + j], zk[c]);
      zq[c] = fmaf(v, wgt[280 + c * 10 + j], zq[c]);
    }
  }
  float mk = zk[0], mq = zq[0];
#pragma unroll
  for (int c = 1; c < 10; ++c) { mk = fmaxf(mk, zk[c]); mq = fmaxf(mq, zq[c]); }
  float sk = 0.f, sq = 0.f;
#pragma unroll
  for (int c = 0; c < 10; ++c) {
    zk[c] = expf(zk[c] - mk); sk += zk[c];
    zq[c] = expf(zq[c] - mq); sq += zq[c];
  }
  float rik = 1.f / sk, riq = 1.f / sq;
#pragma unroll
  for (int c = 0; c < 10; ++c) { zk[c] *= rik; zq[c] *= riq; }

  float mu[10], sgz[10];
#pragma unroll
  for (int c = 0; c < 10; ++c) { mu[c] = wgt[490 + c]; sgz[c] = wgt[600 + c]; }
#pragma unroll
  for (int j = 0; j < 10; ++j) {
    float v = zq[j];
#pragma unroll
    for (int c = 0; c < 10; ++c) {
      mu[c]  = fmaf(v, wgt[390 + c * 10 + j], mu[c]);
      sgz[c] = fmaf(v, wgt[500 + c * 10 + j], sgz[c]);
    }
  }
  float lp = 0.f, qmean = 0.f, best = zq[0];
  int amax = 0;
#pragma unroll
  for (int c = 0; c < 10; ++c) {
    float x = sgz[c];
    float sg = (x > 20.f) ? x : log1pf(expf(x));   // softplus
    float zr = (zk[c] - mu[c]) / sg;
    lp += -0.5f * zr * zr - logf(sg);
    qmean += zq[c];
    if (c > 0 && zq[c] > best) { best = zq[c]; amax = c; }
  }
  lp -= 10.f * 0.91893853320467274f;  // 10 * 0.5*log(2*pi)
  qmean *= 0.1f;

  int pos = ((bidx * 16 + h) * 16 + sIdx) * 64 + d;
  ws[QM_OFF + pos] = qmean;
  ((int*)ws)[AM_OFF + pos] = amax;
#pragma unroll
  for (int c = 0; c < 10; ++c) cqs[(h * 64 + d) * 10 + c] = zq[c];
  __syncthreads();

  // ce: log_softmax over h (axis=1), then sum_h cq*logp, per (d,c)
  float ce = 0.f;
  if (t < 640) {
    int dd = t / 10, cc = t - dd * 10;
    float x[16];
#pragma unroll
    for (int hh = 0; hh < 16; ++hh) x[hh] = cqs[(hh * 64 + dd) * 10 + cc];
    float mx = x[0];
#pragma unroll
    for (int hh = 1; hh < 16; ++hh) mx = fmaxf(mx, x[hh]);
    float sum = 0.f;
#pragma unroll
    for (int hh = 0; hh < 16; ++hh) sum += expf(x[hh] - mx);
    float lse = mx + logf(sum);
#pragma unroll
    for (int hh = 0; hh < 16; ++hh) ce += x[hh] * (x[hh] - lse);
  }

#pragma unroll
  for (int o = 1; o < 64; o <<= 1) { lp += __shfl_xor(lp, o); ce += __shfl_xor(ce, o); }
  __shared__ float redw[16][2];
  if ((t & 63) == 0) { redw[t >> 6][0] = lp; redw[t >> 6][1] = ce; }
  __syncthreads();
  if (t == 0) {
    float Ls = 0.f, Cs = 0.f;
#pragma unroll
    for (int i = 0; i < 16; ++i) { Ls += redw[i][0]; Cs += redw[i][1]; }
    ws[LP_OFF + blockIdx.x] = Ls;
    ws[CE_OFF + blockIdx.x] = Cs;
  }
}

// ---------------- Kernel 3: masked-cluster attention via MFMA ----------------
// grid 256 = bh, block 1024 (16 waves). Setup ONCE per bh; each wave owns 8 q-tiles
// with a rolling 1-deep register Q-prefetch. Per-tile math identical to round 7.
__global__ __launch_bounds__(1024, 1) void k_attn(
    const float* __restrict__ Q, float* __restrict__ out,
    const float* __restrict__ ws)
{
  int bh = blockIdx.x;
  int t = threadIdx.x;
  int wv = t >> 6;            // 0..15
  int l = t & 63;
  int l15 = l & 15;
  int sbase = (l >> 4) * 8;   // k-chunk base of A/B frags
  int g4 = (l >> 4) * 4;      // row base of C/D frags

  __shared__ unsigned short Gm[10][16][72];     // bf16 bits, d padded 64->72 (bank spread)
  __shared__ float Vs_l[1024];
  __shared__ unsigned short attn_l[16][16][32]; // per-wave [q][s], s>=16 stays zero

  const float* __restrict__ qmp = ws + QM_OFF + bh * 1024;
  const int* __restrict__ amp = (const int*)ws + AM_OFF + bh * 1024;
  const float* __restrict__ vsp = ws + VS_OFF + bh * 1024;

  // Q base for this wave: rows wv*128 .. +127 (8 tiles of 16)
  const float* __restrict__ qbp =
      Q + ((size_t)bh * 2048 + wv * 128 + l15) * 64 + sbase;

  // issue tile 0's loads immediately (latency hidden by setup)
  float4 qA[4], qB[4];
#pragma unroll
  for (int e = 0; e < 4; ++e)
    qA[e] = *(const float4*)(qbp + (e >> 1) * 32 + (e & 1) * 4);

  for (int i = t; i < 5760; i += 1024) ((unsigned*)Gm)[i] = 0u;
  for (int i = t; i < 4096; i += 1024) ((unsigned*)attn_l)[i] = 0u;
  Vs_l[t] = vsp[t];
  __syncthreads();
  Gm[amp[t]][t >> 6][t & 63] = bfb(qmp[t]);   // masked q_mean; empty clusters stay all-zero
  __syncthreads();

  union Frag { unsigned u[4]; short8 s8; };

  // Vs^T A-frags (M=d, K=s padded to 32 with zeros), hoisted per wave
  Frag vf[4];
#pragma unroll
  for (int dt = 0; dt < 4; ++dt) {
#pragma unroll
    for (int e2 = 0; e2 < 4; ++e2) {
      int s0 = sbase + e2 * 2;
      float a = (s0 < 16) ? Vs_l[s0 * 64 + dt * 16 + l15] : 0.f;
      float b = (s0 + 1 < 16) ? Vs_l[(s0 + 1) * 64 + dt * 16 + l15] : 0.f;
      vf[dt].u[e2] = pk2(a, b);
    }
  }

#pragma unroll
  for (int tt = 0; tt < 8; ++tt) {
    // issue next tile's loads into the other buffer (fully unrolled -> static regs)
    if (tt < 7) {
      const float* np = qbp + (size_t)(tt + 1) * 1024;
      float4* nxt = (tt & 1) ? qA : qB;
#pragma unroll
      for (int e = 0; e < 4; ++e)
        nxt[e] = *(const float4*)(np + (e >> 1) * 32 + (e & 1) * 4);
    }
    const float4* cur = (tt & 1) ? qB : qA;

    // B-frags = Q^T from prefetched registers
    Frag bf[2];
#pragma unroll
    for (int ks = 0; ks < 2; ++ks) {
      float4 a = cur[ks * 2];
      float4 b2 = cur[ks * 2 + 1];
      bf[ks].u[0] = pk2(a.x, a.y);
      bf[ks].u[1] = pk2(a.z, a.w);
      bf[ks].u[2] = pk2(b2.x, b2.y);
      bf[ks].u[3] = pk2(b2.z, b2.w);
    }

    f32x4 acc[10];
#pragma unroll
    for (int c = 0; c < 10; ++c) acc[c] = (f32x4){0.f, 0.f, 0.f, 0.f};
#pragma unroll
    for (int ks = 0; ks < 2; ++ks) {
#pragma unroll
      for (int c = 0; c < 10; ++c) {
        short8 af = *(const short8*)(const void*)&Gm[c][l15][sbase + ks * 32];
        acc[c] = __builtin_amdgcn_mfma_f32_16x16x32_bf16(af, bf[ks].s8, acc[c], 0, 0, 0);
      }
    }
    // max over clusters (empty clusters contribute their all-zero tile, as in the reference)
    f32x4 fs = acc[0];
#pragma unroll
    for (int c = 1; c < 10; ++c) {
      fs.x = fmaxf(fs.x, acc[c].x); fs.y = fmaxf(fs.y, acc[c].y);
      fs.z = fmaxf(fs.z, acc[c].z); fs.w = fmaxf(fs.w, acc[c].w);
    }
    // softmax over s = row dim: reduce 4 regs + lane-groups (xor 16, 32)
    float mx = fmaxf(fmaxf(fs.x, fs.y), fmaxf(fs.z, fs.w));
    mx = fmaxf(mx, __shfl_xor(mx, 16));
    mx = fmaxf(mx, __shfl_xor(mx, 32));
    float e0 = __expf(fs.x - mx), e1 = __expf(fs.y - mx),
          e2 = __expf(fs.z - mx), e3 = __expf(fs.w - mx);
    float ssum = e0 + e1 + e2 + e3;
    ssum += __shfl_xor(ssum, 16);
    ssum += __shfl_xor(ssum, 32);
    float inv = 1.f / ssum;
    // bounce attn through wave-private LDS to reach the B-frag layout
    unsigned* awp = (unsigned*)&attn_l[wv][l15][g4];
    awp[0] = pk2(e0 * inv, e1 * inv);
    awp[1] = pk2(e2 * inv, e3 * inv);
    short8 b2f = *(const short8*)(const void*)&attn_l[wv][l15][sbase];
#pragma unroll
    for (int dt = 0; dt < 4; ++dt) {
      f32x4 ct = (f32x4){0.f, 0.f, 0.f, 0.f};
      ct = __builtin_amdgcn_mfma_f32_16x16x32_bf16(vf[dt].s8, b2f, ct, 0, 0, 0);
      float* op = out + ((size_t)bh * 2048 + wv * 128 + tt * 16 + l15) * 64 + dt * 16 + g4;
      *(f32x4*)op = ct;
    }
  }

  // loss = -mean(log_prob) + ce   (deterministic sum of per-block partials)
  if (bh == 0 && t == 0) {
    float Ls = 0.f, Cs = 0.f;
    for (int i = 0; i < 256; ++i) { Ls += ws[LP_OFF + i]; Cs += ws[CE_OFF + i]; }
    out[33554432] = -Ls / 2621440.f - Cs / 163840.f;
  }
}

extern "C" void kernel_launch(void* const* d_in, const int* in_sizes, int n_in,
                              void* d_out, int out_size, void* d_ws, size_t ws_size,
                              hipStream_t stream) {
  const float* Q   = (const float*)d_in[0];
  const float* K   = (const float*)d_in[1];
  const float* V   = (const float*)d_in[2];
  const float* skw = (const float*)d_in[3];
  const float* skb = (const float*)d_in[4];
  const float* svw = (const float*)d_in[5];
  const float* svb = (const float*)d_in[6];
  const float* pw  = (const float*)d_in[7];
  const float* pb  = (const float*)d_in[8];
  const float* ckw = (const float*)d_in[9];
  const float* ckb = (const float*)d_in[10];
  const float* cqw = (const float*)d_in[11];
  const float* cqb = (const float*)d_in[12];
  const float* muw = (const float*)d_in[13];
  const float* mub = (const float*)d_in[14];
  const float* sgw = (const float*)d_in[15];
  const float* sgb = (const float*)d_in[16];
  float* out = (float*)d_out;
  float* ws  = (float*)d_ws;

  hipLaunchKernelGGL(k_shrink6, dim3(2048), dim3(256), 0, stream, K, V, skw, svw, out);
  hipLaunchKernelGGL(k_shrink_red, dim3(512), dim3(256), 0, stream, out, skb, svb, ws);
  hipLaunchKernelGGL(k_cluster, dim3(256), dim3(1024), 0, stream,
                     pw, pb, ckw, ckb, cqw, cqb, muw, mub, sgw, sgb, ws);
  hipLaunchKernelGGL(k_attn, dim3(256), dim3(1024), 0, stream, Q, out, ws);
}

// Round 9
// 276.759 us; speedup vs baseline: 1.0957x; 1.0957x over previous
//
#include <hip/hip_runtime.h>

// Clustering attention for MI355X.
// ws float-offsets (round-1-proven 4.2 MB footprint)
#define KS_OFF 0
#define VS_OFF 262144
#define QM_OFF 524288
#define AM_OFF 786432
#define LP_OFF 1048576
#define CE_OFF 1048832

typedef __attribute__((ext_vector_type(8))) short short8;
typedef __attribute__((ext_vector_type(4))) float f32x4;

__device__ inline unsigned short bfb(float x) {
  unsigned u = __float_as_uint(x);
  return (unsigned short)((u + 0x7fffu + ((u >> 16) & 1u)) >> 16);
}
__device__ inline unsigned pk2(float a, float b) {
  return (unsigned)bfb(a) | ((unsigned)bfb(b) << 16);
}
__device__ inline float bft(unsigned short h) {
  return __uint_as_float((unsigned)h << 16);
}
// 3-way split: x = bft(h)+bft(m)+bft(l) + eps, |eps| <= ~2^-25 |x|.
__device__ inline void split3(float x, unsigned short& h, unsigned short& m, unsigned short& l) {
  unsigned u = __float_as_uint(x);
  h = (unsigned short)(u >> 16);
  float r = x - bft(h);
  m = (unsigned short)(__float_as_uint(r) >> 16);
  float r2 = r - bft(m);
  l = bfb(r2);
}

// ---------------- Kernel 1a: shrink partials, nontemporal reg-staged pipeline ----------------
// grid 2048 = (tensor,bh,quarter), block 256 (4 waves). Wave-private 8KB LDS band
// (write rows wv*32..+31, read the same) -> NO barriers in the main loop; each wave
// free-runs a 1-deep register pipeline. K/V reads are NON-TEMPORAL (single-use):
// stop L3 allocation/churn, test the ~3.45 TB/s read-path pin. Math = round 6/7.
__global__ __launch_bounds__(256) void k_shrink7(
    const float* __restrict__ K, const float* __restrict__ V,
    const float* __restrict__ skw, const float* __restrict__ svw,
    float* __restrict__ part)
{
  int blk = blockIdx.x;
  int q = blk & 3;
  int bh = (blk >> 2) & 255;
  int tensor = blk >> 10;      // 0 = K, 1 = V
  const float* __restrict__ src = (tensor ? V : K) + (size_t)bh * (4096 * 64);
  const float* __restrict__ w   = tensor ? svw : skw;
  float* __restrict__ dst = part + (size_t)blk * 1024;

  int t = threadIdx.x;
  int wv = t >> 6;
  int l = t & 63;
  int l15 = l & 15;
  int kg = l >> 4;             // 0..3
  int lr4 = l >> 4;            // row-in-chunk for staging
  union Frag { unsigned u[4]; short8 s8; };

  __shared__ float shm[8192];            // 32 KB: 4 wave-private 8KB bands
  float* __restrict__ my = shm + wv * 2048;

  // load subtile 'sub' (this wave's 32-row band) into regs, non-temporally
#define STAGE_LOAD(sub) do {                                                  \
    const float* gs = src + (size_t)(q * 1024 + (sub) * 128 + wv * 32) * 64;  \
    _Pragma("unroll")                                                         \
    for (int i = 0; i < 8; ++i) {                                             \
      int rl = i * 4 + lr4;                                                   \
      int s16 = (l & 15) ^ (((rl >> 3) & 3) << 2);                            \
      ld[i] = __builtin_nontemporal_load((const f32x4*)(gs + rl * 64 + s16 * 4)); \
    } } while (0)

  f32x4 ld[8];
  f32x4 acc[4];
#pragma unroll
  for (int nt = 0; nt < 4; ++nt) acc[nt] = (f32x4){0.f, 0.f, 0.f, 0.f};

  const float* __restrict__ wrow = w + l15 * 4096 + kg * 8;

  STAGE_LOAD(0);
  int kk0 = q * 32 + wv;
  float4 wa_c = *(const float4*)(wrow + kk0 * 32);
  float4 wb_c = *(const float4*)(wrow + kk0 * 32 + 4);

  for (int sub = 0; sub < 8; ++sub) {
    // write current regs into the wave-private band (swizzled layout)
#pragma unroll
    for (int i = 0; i < 8; ++i)
      *(f32x4*)&my[(i * 4 + lr4) * 64 + (l & 15) * 4] = ld[i];

    // issue next subtile's loads (in flight through the whole compute phase)
    if (sub < 7) STAGE_LOAD(sub + 1);
    float4 wa_n, wb_n;
    if (sub < 7) {
      int kkn = q * 32 + (sub + 1) * 4 + wv;
      wa_n = *(const float4*)(wrow + kkn * 32);
      wb_n = *(const float4*)(wrow + kkn * 32 + 4);
    }

    // A-frags from w
    float we[8] = {wa_c.x, wa_c.y, wa_c.z, wa_c.w, wb_c.x, wb_c.y, wb_c.z, wb_c.w};
    Frag ah, am, al;
#pragma unroll
    for (int e = 0; e < 4; ++e) {
      unsigned short h0, m0, l0, h1, m1, l1;
      split3(we[2 * e], h0, m0, l0);
      split3(we[2 * e + 1], h1, m1, l1);
      ah.u[e] = (unsigned)h0 | ((unsigned)h1 << 16);
      am.u[e] = (unsigned)m0 | ((unsigned)m1 << 16);
      al.u[e] = (unsigned)l0 | ((unsigned)l1 << 16);
    }

    // B-frags from the wave-private band (swizzled read) + split-precision MFMA
#pragma unroll
    for (int nt = 0; nt < 4; ++nt) {
      float v[8];
#pragma unroll
      for (int j = 0; j < 8; ++j) {
        int rl = kg * 8 + j;
        int col = (nt * 16 + l15) ^ (((rl >> 3) & 3) << 4);
        v[j] = my[rl * 64 + col];
      }
      Frag bh, bm, bl;
#pragma unroll
      for (int e = 0; e < 4; ++e) {
        unsigned short h0, m0, l0, h1, m1, l1;
        split3(v[2 * e], h0, m0, l0);
        split3(v[2 * e + 1], h1, m1, l1);
        bh.u[e] = (unsigned)h0 | ((unsigned)h1 << 16);
        bm.u[e] = (unsigned)m0 | ((unsigned)m1 << 16);
        bl.u[e] = (unsigned)l0 | ((unsigned)l1 << 16);
      }
      // (h+m+l)*(h+m+l): keep hh, hm, mh, hl, lh, mm  (dropped terms <= ~2^-24)
      acc[nt] = __builtin_amdgcn_mfma_f32_16x16x32_bf16(ah.s8, bh.s8, acc[nt], 0, 0, 0);
      acc[nt] = __builtin_amdgcn_mfma_f32_16x16x32_bf16(ah.s8, bm.s8, acc[nt], 0, 0, 0);
      acc[nt] = __builtin_amdgcn_mfma_f32_16x16x32_bf16(am.s8, bh.s8, acc[nt], 0, 0, 0);
      acc[nt] = __builtin_amdgcn_mfma_f32_16x16x32_bf16(ah.s8, bl.s8, acc[nt], 0, 0, 0);
      acc[nt] = __builtin_amdgcn_mfma_f32_16x16x32_bf16(al.s8, bh.s8, acc[nt], 0, 0, 0);
      acc[nt] = __builtin_amdgcn_mfma_f32_16x16x32_bf16(am.s8, bm.s8, acc[nt], 0, 0, 0);
    }

    if (sub < 7) { wa_c = wa_n; wb_c = wb_n; }
  }

  // ---- cross-wave reduce (the only barriers in the kernel) ----
  __syncthreads();
  int g4 = kg * 4;
#pragma unroll
  for (int nt = 0; nt < 4; ++nt)
#pragma unroll
    for (int r = 0; r < 4; ++r)
      shm[wv * 1024 + (g4 + r) * 64 + nt * 16 + l15] = acc[nt][r];
  __syncthreads();
  for (int p = t; p < 1024; p += 256)
    dst[p] = shm[p] + shm[1024 + p] + shm[2048 + p] + shm[3072 + p];
#undef STAGE_LOAD
}

// ---------------- Kernel 1b: reduce 4 quarter-partials + bias -> ws ----------------
__global__ __launch_bounds__(256) void k_shrink_red(
    const float* __restrict__ part, const float* __restrict__ skb,
    const float* __restrict__ svb, float* __restrict__ ws)
{
  int blk = blockIdx.x;        // 512 = (tensor,bh)
  int tensor = blk >> 8;
  int bh = blk & 255;
  const float* __restrict__ p0 = part + ((size_t)(tensor * 1024 + bh * 4)) * 1024;
  const float* __restrict__ bias = tensor ? svb : skb;
  float* __restrict__ dst = ws + (tensor ? VS_OFF : KS_OFF) + bh * 1024;
  for (int p = threadIdx.x; p < 1024; p += 256)
    dst[p] = ((p0[p] + p0[1024 + p]) + (p0[2048 + p] + p0[3072 + p])) + bias[p >> 6];
}

// ---------------- Kernel 2: cluster nets + loss partials + (q_mean, argmax) ----------------
// grid 256 = (b,s), block 1024 = (h,d). LDS holds cq for the h-axis log_softmax.
__global__ __launch_bounds__(1024) void k_cluster(
    const float* __restrict__ pw, const float* __restrict__ pb,
    const float* __restrict__ ckw, const float* __restrict__ ckb,
    const float* __restrict__ cqw, const float* __restrict__ cqb,
    const float* __restrict__ muw, const float* __restrict__ mub,
    const float* __restrict__ sgw, const float* __restrict__ sgb,
    float* __restrict__ ws)
{
  int bidx = blockIdx.x >> 4;   // batch index i of the unfold
  int sIdx = blockIdx.x & 15;
  int t = threadIdx.x;
  int h = t >> 6, d = t & 63;

  __shared__ float wgt[610];    // pw160|pb10|ckw100|ckb10|cqw100|cqb10|muw100|mub10|sgw100|sgb10
  __shared__ float cqs[16 * 64 * 10];
  if (t < 160) wgt[t] = pw[t];
  else if (t < 170) wgt[t] = pb[t - 160];
  else if (t < 270) wgt[t] = ckw[t - 170];
  else if (t < 280) wgt[t] = ckb[t - 270];
  else if (t < 380) wgt[t] = cqw[t - 280];
  else if (t < 390) wgt[t] = cqb[t - 380];
  else if (t < 490) wgt[t] = muw[t - 390];
  else if (t < 500) wgt[t] = mub[t - 490];
  else if (t < 600) wgt[t] = sgw[t - 500];
  else if (t < 610) wgt[t] = sgb[t - 600];
  __syncthreads();

  const float* __restrict__ Ks = ws + KS_OFF;

  // K_unfold[i,h,s,d,j] = (i+j<16) ? 0 : Ks[i+j-15]; proj over j => sum_{m=1..i} Ks[m]*pw[c][m+15-i]
  float ckp[10];
#pragma unroll
  for (int c = 0; c < 10; ++c) ckp[c] = wgt[160 + c];
  for (int m = 1; m <= bidx; ++m) {
    float kv = Ks[((m * 16 + h) * 16 + sIdx) * 64 + d];
    int j = m + 15 - bidx;
#pragma unroll
    for (int c = 0; c < 10; ++c) ckp[c] = fmaf(kv, wgt[c * 16 + j], ckp[c]);
  }
#pragma unroll
  for (int c = 0; c < 10; ++c) ckp[c] = fmaxf(ckp[c], 0.f);

  float zk[10], zq[10];
#pragma unroll
  for (int c = 0; c < 10; ++c) { zk[c] = wgt[270 + c]; zq[c] = wgt[380 + c]; }
#pragma unroll
  for (int j = 0; j < 10; ++j) {
    float v = ckp[j];
#pragma unroll
    for (int c = 0; c < 10; ++c) {
      zk[c] = fmaf(v, wgt[170 + c * 10 + j], zk[c]);
      zq[c] = fmaf(v, wgt[280 + c * 10 + j], zq[c]);
    }
  }
  float mk = zk[0], mq = zq[0];
#pragma unroll
  for (int c = 1; c < 10; ++c) { mk = fmaxf(mk, zk[c]); mq = fmaxf(mq, zq[c]); }
  float sk = 0.f, sq = 0.f;
#pragma unroll
  for (int c = 0; c < 10; ++c) {
    zk[c] = expf(zk[c] - mk); sk += zk[c];
    zq[c] = expf(zq[c] - mq); sq += zq[c];
  }
  float rik = 1.f / sk, riq = 1.f / sq;
#pragma unroll
  for (int c = 0; c < 10; ++c) { zk[c] *= rik; zq[c] *= riq; }

  float mu[10], sgz[10];
#pragma unroll
  for (int c = 0; c < 10; ++c) { mu[c] = wgt[490 + c]; sgz[c] = wgt[600 + c]; }
#pragma unroll
  for (int j = 0; j < 10; ++j) {
    float v = zq[j];
#pragma unroll
    for (int c = 0; c < 10; ++c) {
      mu[c]  = fmaf(v, wgt[390 + c * 10 + j], mu[c]);
      sgz[c] = fmaf(v, wgt[500 + c * 10 + j], sgz[c]);
    }
  }
  float lp = 0.f, qmean = 0.f, best = zq[0];
  int amax = 0;
#pragma unroll
  for (int c = 0; c < 10; ++c) {
    float x = sgz[c];
    float sg = (x > 20.f) ? x : log1pf(expf(x));   // softplus
    float zr = (zk[c] - mu[c]) / sg;
    lp += -0.5f * zr * zr - logf(sg);
    qmean += zq[c];
    if (c > 0 && zq[c] > best) { best = zq[c]; amax = c; }
  }
  lp -= 10.f * 0.91893853320467274f;  // 10 * 0.5*log(2*pi)
  qmean *= 0.1f;

  int pos = ((bidx * 16 + h) * 16 + sIdx) * 64 + d;
  ws[QM_OFF + pos] = qmean;
  ((int*)ws)[AM_OFF + pos] = amax;
#pragma unroll
  for (int c = 0; c < 10; ++c) cqs[(h * 64 + d) * 10 + c] = zq[c];
  __syncthreads();

  // ce: log_softmax over h (axis=1), then sum_h cq*logp, per (d,c)
  float ce = 0.f;
  if (t < 640) {
    int dd = t / 10, cc = t - dd * 10;
    float x[16];
#pragma unroll
    for (int hh = 0; hh < 16; ++hh) x[hh] = cqs[(hh * 64 + dd) * 10 + cc];
    float mx = x[0];
#pragma unroll
    for (int hh = 1; hh < 16; ++hh) mx = fmaxf(mx, x[hh]);
    float sum = 0.f;
#pragma unroll
    for (int hh = 0; hh < 16; ++hh) sum += expf(x[hh] - mx);
    float lse = mx + logf(sum);
#pragma unroll
    for (int hh = 0; hh < 16; ++hh) ce += x[hh] * (x[hh] - lse);
  }

#pragma unroll
  for (int o = 1; o < 64; o <<= 1) { lp += __shfl_xor(lp, o); ce += __shfl_xor(ce, o); }
  __shared__ float redw[16][2];
  if ((t & 63) == 0) { redw[t >> 6][0] = lp; redw[t >> 6][1] = ce; }
  __syncthreads();
  if (t == 0) {
    float Ls = 0.f, Cs = 0.f;
#pragma unroll
    for (int i = 0; i < 16; ++i) { Ls += redw[i][0]; Cs += redw[i][1]; }
    ws[LP_OFF + blockIdx.x] = Ls;
    ws[CE_OFF + blockIdx.x] = Cs;
  }
}

// ---------------- Kernel 3: masked-cluster attention via MFMA ----------------
// grid 2048 = (bh, eighth), block 512 (8 waves) — round-7 structure.
// Q loads and context stores are NON-TEMPORAL (single-use streams).
__global__ __launch_bounds__(512, 2) void k_attn(
    const float* __restrict__ Q, float* __restrict__ out,
    const float* __restrict__ ws)
{
  int bid = blockIdx.x;
  int bh = bid >> 3;
  int eighth = bid & 7;
  int t = threadIdx.x;
  int wv = t >> 6;
  int l = t & 63;
  int l15 = l & 15;
  int sbase = (l >> 4) * 8;   // k-chunk base of A/B frags
  int g4 = (l >> 4) * 4;      // row base of C/D frags

  __shared__ unsigned short Gm[10][16][72];     // bf16 bits, d padded 64->72 (bank spread)
  __shared__ float Vs_l[1024];
  __shared__ unsigned short attn_l[8][16][32];  // per-wave [q][s], s>=16 stays zero

  const float* __restrict__ qmp = ws + QM_OFF + bh * 1024;
  const int* __restrict__ amp = (const int*)ws + AM_OFF + bh * 1024;
  const float* __restrict__ vsp = ws + VS_OFF + bh * 1024;

  // hoisted Q loads: base for this wave's q-rows; tt=0 issued NOW (latency hidden by staging)
  const float* __restrict__ qbp =
      Q + ((size_t)bh * 2048 + eighth * 256 + wv * 32 + l15) * 64 + sbase;
  f32x4 q4[2][4];
#pragma unroll
  for (int e = 0; e < 4; ++e)
    q4[0][e] = __builtin_nontemporal_load(
        (const f32x4*)(qbp + (e >> 1) * 32 + (e & 1) * 4));

  for (int i = t; i < 5760; i += 512) ((unsigned*)Gm)[i] = 0u;
  for (int i = t; i < 2048; i += 512) ((unsigned*)attn_l)[i] = 0u;
  for (int i = t; i < 1024; i += 512) Vs_l[i] = vsp[i];
  __syncthreads();
  for (int p = t; p < 1024; p += 512) {
    int s = p >> 6, dd = p & 63;
    Gm[amp[p]][s][dd] = bfb(qmp[p]);   // masked q_mean; empty clusters stay all-zero
  }
  __syncthreads();

  union Frag { unsigned u[4]; short8 s8; };

  // Vs^T A-frags (M=d, K=s padded to 32 with zeros), hoisted per wave
  Frag vf[4];
#pragma unroll
  for (int dt = 0; dt < 4; ++dt) {
#pragma unroll
    for (int e2 = 0; e2 < 4; ++e2) {
      int s0 = sbase + e2 * 2;
      float a = (s0 < 16) ? Vs_l[s0 * 64 + dt * 16 + l15] : 0.f;
      float b = (s0 + 1 < 16) ? Vs_l[(s0 + 1) * 64 + dt * 16 + l15] : 0.f;
      vf[dt].u[e2] = pk2(a, b);
    }
  }

#pragma unroll
  for (int tt = 0; tt < 2; ++tt) {
    int qbase = eighth * 256 + wv * 32 + tt * 16;
    if (tt == 0) {   // issue tt=1 loads early; latency hidden by tt=0 compute
#pragma unroll
      for (int e = 0; e < 4; ++e)
        q4[1][e] = __builtin_nontemporal_load(
            (const f32x4*)(qbp + 1024 + (e >> 1) * 32 + (e & 1) * 4));
    }

    // B-frags = Q^T from prefetched registers
    Frag bf[2];
#pragma unroll
    for (int ks = 0; ks < 2; ++ks) {
      f32x4 a = q4[tt][ks * 2];
      f32x4 b2 = q4[tt][ks * 2 + 1];
      bf[ks].u[0] = pk2(a.x, a.y);
      bf[ks].u[1] = pk2(a.z, a.w);
      bf[ks].u[2] = pk2(b2.x, b2.y);
      bf[ks].u[3] = pk2(b2.z, b2.w);
    }

    f32x4 acc[10];
#pragma unroll
    for (int c = 0; c < 10; ++c) acc[c] = (f32x4){0.f, 0.f, 0.f, 0.f};
#pragma unroll
    for (int ks = 0; ks < 2; ++ks) {
#pragma unroll
      for (int c = 0; c < 10; ++c) {
        short8 af = *(const short8*)(const void*)&Gm[c][l15][sbase + ks * 32];
        acc[c] = __builtin_amdgcn_mfma_f32_16x16x32_bf16(af, bf[ks].s8, acc[c], 0, 0, 0);
      }
    }
    // max over clusters (empty clusters contribute their all-zero tile, as in the reference)
    f32x4 fs = acc[0];
#pragma unroll
    for (int c = 1; c < 10; ++c) {
      fs.x = fmaxf(fs.x, acc[c].x); fs.y = fmaxf(fs.y, acc[c].y);
      fs.z = fmaxf(fs.z, acc[c].z); fs.w = fmaxf(fs.w, acc[c].w);
    }
    // softmax over s = row dim: reduce 4 regs + lane-groups (xor 16, 32)
    float mx = fmaxf(fmaxf(fs.x, fs.y), fmaxf(fs.z, fs.w));
    mx = fmaxf(mx, __shfl_xor(mx, 16));
    mx = fmaxf(mx, __shfl_xor(mx, 32));
    float e0 = __expf(fs.x - mx), e1 = __expf(fs.y - mx),
          e2 = __expf(fs.z - mx), e3 = __expf(fs.w - mx);
    float ssum = e0 + e1 + e2 + e3;
    ssum += __shfl_xor(ssum, 16);
    ssum += __shfl_xor(ssum, 32);
    float inv = 1.f / ssum;
    // bounce attn through wave-private LDS to reach the B-frag layout
    unsigned* awp = (unsigned*)&attn_l[wv][l15][g4];
    awp[0] = pk2(e0 * inv, e1 * inv);
    awp[1] = pk2(e2 * inv, e3 * inv);
    short8 b2f = *(const short8*)(const void*)&attn_l[wv][l15][sbase];
#pragma unroll
    for (int dt = 0; dt < 4; ++dt) {
      f32x4 ct = (f32x4){0.f, 0.f, 0.f, 0.f};
      ct = __builtin_amdgcn_mfma_f32_16x16x32_bf16(vf[dt].s8, b2f, ct, 0, 0, 0);
      float* op = out + ((size_t)bh * 2048 + qbase + l15) * 64 + dt * 16 + g4;
      __builtin_nontemporal_store(ct, (f32x4*)op);
    }
  }

  // loss = -mean(log_prob) + ce   (deterministic sum of per-block partials)
  if (bid == 0 && t == 0) {
    float Ls = 0.f, Cs = 0.f;
    for (int i = 0; i < 256; ++i) { Ls += ws[LP_OFF + i]; Cs += ws[CE_OFF + i]; }
    out[33554432] = -Ls / 2621440.f - Cs / 163840.f;
  }
}

extern "C" void kernel_launch(void* const* d_in, const int* in_sizes, int n_in,
                              void* d_out, int out_size, void* d_ws, size_t ws_size,
                              hipStream_t stream) {
  const float* Q   = (const float*)d_in[0];
  const float* K   = (const float*)d_in[1];
  const float* V   = (const float*)d_in[2];
  const float* skw = (const float*)d_in[3];
  const float* skb = (const float*)d_in[4];
  const float* svw = (const float*)d_in[5];
  const float* svb = (const float*)d_in[6];
  const float* pw  = (const float*)d_in[7];
  const float* pb  = (const float*)d_in[8];
  const float* ckw = (const float*)d_in[9];
  const float* ckb = (const float*)d_in[10];
  const float* cqw = (const float*)d_in[11];
  const float* cqb = (const float*)d_in[12];
  const float* muw = (const float*)d_in[13];
  const float* mub = (const float*)d_in[14];
  const float* sgw = (const float*)d_in[15];
  const float* sgb = (const float*)d_in[16];
  float* out = (float*)d_out;
  float* ws  = (float*)d_ws;

  hipLaunchKernelGGL(k_shrink7, dim3(2048), dim3(256), 0, stream, K, V, skw, svw, out);
  hipLaunchKernelGGL(k_shrink_red, dim3(512), dim3(256), 0, stream, out, skb, svb, ws);
  hipLaunchKernelGGL(k_cluster, dim3(256), dim3(1024), 0, stream,
                     pw, pb, ckw, ckb, cqw, cqb, muw, mub, sgw, sgb, ws);
  hipLaunchKernelGGL(k_attn, dim3(2048), dim3(512), 0, stream, Q, out, ws);
}

// Round 10
// 270.761 us; speedup vs baseline: 1.1200x; 1.0222x over previous
//
#include <hip/hip_runtime.h>

// Clustering attention for MI355X.
// ws float-offsets (round-1-proven 4.2 MB footprint)
#define KS_OFF 0
#define VS_OFF 262144
#define QM_OFF 524288
#define AM_OFF 786432
#define LP_OFF 1048576
#define CE_OFF 1048832

typedef __attribute__((ext_vector_type(8))) short short8;
typedef __attribute__((ext_vector_type(4))) float f32x4;

__device__ inline unsigned short bfb(float x) {
  unsigned u = __float_as_uint(x);
  return (unsigned short)((u + 0x7fffu + ((u >> 16) & 1u)) >> 16);
}
__device__ inline unsigned pk2(float a, float b) {
  return (unsigned)bfb(a) | ((unsigned)bfb(b) << 16);
}
__device__ inline float bft(unsigned short h) {
  return __uint_as_float((unsigned)h << 16);
}
// 3-way split: x = bft(h)+bft(m)+bft(l) + eps, |eps| <= ~2^-25 |x|.
__device__ inline void split3(float x, unsigned short& h, unsigned short& m, unsigned short& l) {
  unsigned u = __float_as_uint(x);
  h = (unsigned short)(u >> 16);
  float r = x - bft(h);
  m = (unsigned short)(__float_as_uint(r) >> 16);
  float r2 = r - bft(m);
  l = bfb(r2);
}

// ---------------- Kernel 1: shrink K,V -> ws directly (no partials, no red) ----------------
// grid 512 = (tensor,bh), block 256 (4 waves). Wave-private 8KB LDS band, NT loads,
// 1-deep register pipeline, no barriers in main loop. Each wave: 32 sub-tiles (kk=sub*4+wv).
// Cross-wave reduce + bias -> ws. Math identical to round 9 (split-precision 6-MFMA ladder).
__global__ __launch_bounds__(256) void k_shrink8(
    const float* __restrict__ K, const float* __restrict__ V,
    const float* __restrict__ skw, const float* __restrict__ skb,
    const float* __restrict__ svw, const float* __restrict__ svb,
    float* __restrict__ ws)
{
  int blk = blockIdx.x;
  int tensor = blk >> 8;       // 0 = K, 1 = V
  int bh = blk & 255;
  const float* __restrict__ src = (tensor ? V : K) + (size_t)bh * (4096 * 64);
  const float* __restrict__ w    = tensor ? svw : skw;
  const float* __restrict__ bias = tensor ? svb : skb;
  float* __restrict__ dst = ws + (tensor ? VS_OFF : KS_OFF) + bh * 1024;

  int t = threadIdx.x;
  int wv = t >> 6;
  int l = t & 63;
  int l15 = l & 15;
  int kg = l >> 4;             // 0..3
  int lr4 = l >> 4;            // row-in-chunk for staging
  union Frag { unsigned u[4]; short8 s8; };

  __shared__ float shm[8192];            // 32 KB: 4 wave-private 8KB bands
  float* __restrict__ my = shm + wv * 2048;

  // load subtile 'sub' (this wave's 32-row band) into regs, non-temporally
#define STAGE_LOAD(sub) do {                                                  \
    const float* gs = src + (size_t)((sub) * 128 + wv * 32) * 64;             \
    _Pragma("unroll")                                                         \
    for (int i = 0; i < 8; ++i) {                                             \
      int rl = i * 4 + lr4;                                                   \
      int s16 = (l & 15) ^ (((rl >> 3) & 3) << 2);                            \
      ld[i] = __builtin_nontemporal_load((const f32x4*)(gs + rl * 64 + s16 * 4)); \
    } } while (0)

  f32x4 ld[8];
  f32x4 acc[4];
#pragma unroll
  for (int nt = 0; nt < 4; ++nt) acc[nt] = (f32x4){0.f, 0.f, 0.f, 0.f};

  const float* __restrict__ wrow = w + l15 * 4096 + kg * 8;

  STAGE_LOAD(0);
  float4 wa_c = *(const float4*)(wrow + wv * 32);
  float4 wb_c = *(const float4*)(wrow + wv * 32 + 4);

  for (int sub = 0; sub < 32; ++sub) {
    // write current regs into the wave-private band (swizzled layout)
#pragma unroll
    for (int i = 0; i < 8; ++i)
      *(f32x4*)&my[(i * 4 + lr4) * 64 + (l & 15) * 4] = ld[i];

    // issue next subtile's loads (in flight through the whole compute phase)
    if (sub < 31) STAGE_LOAD(sub + 1);
    float4 wa_n, wb_n;
    if (sub < 31) {
      int kkn = (sub + 1) * 4 + wv;
      wa_n = *(const float4*)(wrow + kkn * 32);
      wb_n = *(const float4*)(wrow + kkn * 32 + 4);
    }

    // A-frags from w
    float we[8] = {wa_c.x, wa_c.y, wa_c.z, wa_c.w, wb_c.x, wb_c.y, wb_c.z, wb_c.w};
    Frag ah, am, al;
#pragma unroll
    for (int e = 0; e < 4; ++e) {
      unsigned short h0, m0, l0, h1, m1, l1;
      split3(we[2 * e], h0, m0, l0);
      split3(we[2 * e + 1], h1, m1, l1);
      ah.u[e] = (unsigned)h0 | ((unsigned)h1 << 16);
      am.u[e] = (unsigned)m0 | ((unsigned)m1 << 16);
      al.u[e] = (unsigned)l0 | ((unsigned)l1 << 16);
    }

    // B-frags from the wave-private band (swizzled read) + split-precision MFMA
#pragma unroll
    for (int nt = 0; nt < 4; ++nt) {
      float v[8];
#pragma unroll
      for (int j = 0; j < 8; ++j) {
        int rl = kg * 8 + j;
        int col = (nt * 16 + l15) ^ (((rl >> 3) & 3) << 4);
        v[j] = my[rl * 64 + col];
      }
      Frag bh, bm, bl;
#pragma unroll
      for (int e = 0; e < 4; ++e) {
        unsigned short h0, m0, l0, h1, m1, l1;
        split3(v[2 * e], h0, m0, l0);
        split3(v[2 * e + 1], h1, m1, l1);
        bh.u[e] = (unsigned)h0 | ((unsigned)h1 << 16);
        bm.u[e] = (unsigned)m0 | ((unsigned)m1 << 16);
        bl.u[e] = (unsigned)l0 | ((unsigned)l1 << 16);
      }
      // (h+m+l)*(h+m+l): keep hh, hm, mh, hl, lh, mm  (dropped terms <= ~2^-24)
      acc[nt] = __builtin_amdgcn_mfma_f32_16x16x32_bf16(ah.s8, bh.s8, acc[nt], 0, 0, 0);
      acc[nt] = __builtin_amdgcn_mfma_f32_16x16x32_bf16(ah.s8, bm.s8, acc[nt], 0, 0, 0);
      acc[nt] = __builtin_amdgcn_mfma_f32_16x16x32_bf16(am.s8, bh.s8, acc[nt], 0, 0, 0);
      acc[nt] = __builtin_amdgcn_mfma_f32_16x16x32_bf16(ah.s8, bl.s8, acc[nt], 0, 0, 0);
      acc[nt] = __builtin_amdgcn_mfma_f32_16x16x32_bf16(al.s8, bh.s8, acc[nt], 0, 0, 0);
      acc[nt] = __builtin_amdgcn_mfma_f32_16x16x32_bf16(am.s8, bm.s8, acc[nt], 0, 0, 0);
    }

    if (sub < 31) { wa_c = wa_n; wb_c = wb_n; }
  }

  // ---- cross-wave reduce + bias (the only barriers in the kernel) ----
  __syncthreads();
  int g4 = kg * 4;
#pragma unroll
  for (int nt = 0; nt < 4; ++nt)
#pragma unroll
    for (int r = 0; r < 4; ++r)
      shm[wv * 1024 + (g4 + r) * 64 + nt * 16 + l15] = acc[nt][r];
  __syncthreads();
  for (int p = t; p < 1024; p += 256)
    dst[p] = ((shm[p] + shm[1024 + p]) + (shm[2048 + p] + shm[3072 + p])) + bias[p >> 6];
#undef STAGE_LOAD
}

// ---------------- Kernel 2: cluster nets + loss partials + (q_mean, argmax) ----------------
// grid 256 = (b,s), block 1024 = (h,d). LDS holds cq for the h-axis log_softmax.
__global__ __launch_bounds__(1024) void k_cluster(
    const float* __restrict__ pw, const float* __restrict__ pb,
    const float* __restrict__ ckw, const float* __restrict__ ckb,
    const float* __restrict__ cqw, const float* __restrict__ cqb,
    const float* __restrict__ muw, const float* __restrict__ mub,
    const float* __restrict__ sgw, const float* __restrict__ sgb,
    float* __restrict__ ws)
{
  int bidx = blockIdx.x >> 4;   // batch index i of the unfold
  int sIdx = blockIdx.x & 15;
  int t = threadIdx.x;
  int h = t >> 6, d = t & 63;

  __shared__ float wgt[610];    // pw160|pb10|ckw100|ckb10|cqw100|cqb10|muw100|mub10|sgw100|sgb10
  __shared__ float cqs[16 * 64 * 10];
  if (t < 160) wgt[t] = pw[t];
  else if (t < 170) wgt[t] = pb[t - 160];
  else if (t < 270) wgt[t] = ckw[t - 170];
  else if (t < 280) wgt[t] = ckb[t - 270];
  else if (t < 380) wgt[t] = cqw[t - 280];
  else if (t < 390) wgt[t] = cqb[t - 380];
  else if (t < 490) wgt[t] = muw[t - 390];
  else if (t < 500) wgt[t] = mub[t - 490];
  else if (t < 600) wgt[t] = sgw[t - 500];
  else if (t < 610) wgt[t] = sgb[t - 600];
  __syncthreads();

  const float* __restrict__ Ks = ws + KS_OFF;

  // K_unfold[i,h,s,d,j] = (i+j<16) ? 0 : Ks[i+j-15]; proj over j => sum_{m=1..i} Ks[m]*pw[c][m+15-i]
  float ckp[10];
#pragma unroll
  for (int c = 0; c < 10; ++c) ckp[c] = wgt[160 + c];
  for (int m = 1; m <= bidx; ++m) {
    float kv = Ks[((m * 16 + h) * 16 + sIdx) * 64 + d];
    int j = m + 15 - bidx;
#pragma unroll
    for (int c = 0; c < 10; ++c) ckp[c] = fmaf(kv, wgt[c * 16 + j], ckp[c]);
  }
#pragma unroll
  for (int c = 0; c < 10; ++c) ckp[c] = fmaxf(ckp[c], 0.f);

  float zk[10], zq[10];
#pragma unroll
  for (int c = 0; c < 10; ++c) { zk[c] = wgt[270 + c]; zq[c] = wgt[380 + c]; }
#pragma unroll
  for (int j = 0; j < 10; ++j) {
    float v = ckp[j];
#pragma unroll
    for (int c = 0; c < 10; ++c) {
      zk[c] = fmaf(v, wgt[170 + c * 10 + j], zk[c]);
      zq[c] = fmaf(v, wgt[280 + c * 10 + j], zq[c]);
    }
  }
  float mk = zk[0], mq = zq[0];
#pragma unroll
  for (int c = 1; c < 10; ++c) { mk = fmaxf(mk, zk[c]); mq = fmaxf(mq, zq[c]); }
  float sk = 0.f, sq = 0.f;
#pragma unroll
  for (int c = 0; c < 10; ++c) {
    zk[c] = expf(zk[c] - mk); sk += zk[c];
    zq[c] = expf(zq[c] - mq); sq += zq[c];
  }
  float rik = 1.f / sk, riq = 1.f / sq;
#pragma unroll
  for (int c = 0; c < 10; ++c) { zk[c] *= rik; zq[c] *= riq; }

  float mu[10], sgz[10];
#pragma unroll
  for (int c = 0; c < 10; ++c) { mu[c] = wgt[490 + c]; sgz[c] = wgt[600 + c]; }
#pragma unroll
  for (int j = 0; j < 10; ++j) {
    float v = zq[j];
#pragma unroll
    for (int c = 0; c < 10; ++c) {
      mu[c]  = fmaf(v, wgt[390 + c * 10 + j], mu[c]);
      sgz[c] = fmaf(v, wgt[500 + c * 10 + j], sgz[c]);
    }
  }
  float lp = 0.f, qmean = 0.f, best = zq[0];
  int amax = 0;
#pragma unroll
  for (int c = 0; c < 10; ++c) {
    float x = sgz[c];
    float sg = (x > 20.f) ? x : log1pf(expf(x));   // softplus
    float zr = (zk[c] - mu[c]) / sg;
    lp += -0.5f * zr * zr - logf(sg);
    qmean += zq[c];
    if (c > 0 && zq[c] > best) { best = zq[c]; amax = c; }
  }
  lp -= 10.f * 0.91893853320467274f;  // 10 * 0.5*log(2*pi)
  qmean *= 0.1f;

  int pos = ((bidx * 16 + h) * 16 + sIdx) * 64 + d;
  ws[QM_OFF + pos] = qmean;
  ((int*)ws)[AM_OFF + pos] = amax;
#pragma unroll
  for (int c = 0; c < 10; ++c) cqs[(h * 64 + d) * 10 + c] = zq[c];
  __syncthreads();

  // ce: log_softmax over h (axis=1), then sum_h cq*logp, per (d,c)
  float ce = 0.f;
  if (t < 640) {
    int dd = t / 10, cc = t - dd * 10;
    float x[16];
#pragma unroll
    for (int hh = 0; hh < 16; ++hh) x[hh] = cqs[(hh * 64 + dd) * 10 + cc];
    float mx = x[0];
#pragma unroll
    for (int hh = 1; hh < 16; ++hh) mx = fmaxf(mx, x[hh]);
    float sum = 0.f;
#pragma unroll
    for (int hh = 0; hh < 16; ++hh) sum += expf(x[hh] - mx);
    float lse = mx + logf(sum);
#pragma unroll
    for (int hh = 0; hh < 16; ++hh) ce += x[hh] * (x[hh] - lse);
  }

#pragma unroll
  for (int o = 1; o < 64; o <<= 1) { lp += __shfl_xor(lp, o); ce += __shfl_xor(ce, o); }
  __shared__ float redw[16][2];
  if ((t & 63) == 0) { redw[t >> 6][0] = lp; redw[t >> 6][1] = ce; }
  __syncthreads();
  if (t == 0) {
    float Ls = 0.f, Cs = 0.f;
#pragma unroll
    for (int i = 0; i < 16; ++i) { Ls += redw[i][0]; Cs += redw[i][1]; }
    ws[LP_OFF + blockIdx.x] = Ls;
    ws[CE_OFF + blockIdx.x] = Cs;
  }
}

// ---------------- Kernel 3: masked-cluster attention via MFMA ----------------
// grid 2048 = (bh, eighth), block 512 (8 waves) — round-7 structure.
// Q loads and context stores are NON-TEMPORAL (single-use streams).
__global__ __launch_bounds__(512, 2) void k_attn(
    const float* __restrict__ Q, float* __restrict__ out,
    const float* __restrict__ ws)
{
  int bid = blockIdx.x;
  int bh = bid >> 3;
  int eighth = bid & 7;
  int t = threadIdx.x;
  int wv = t >> 6;
  int l = t & 63;
  int l15 = l & 15;
  int sbase = (l >> 4) * 8;   // k-chunk base of A/B frags
  int g4 = (l >> 4) * 4;      // row base of C/D frags

  __shared__ unsigned short Gm[10][16][72];     // bf16 bits, d padded 64->72 (bank spread)
  __shared__ float Vs_l[1024];
  __shared__ unsigned short attn_l[8][16][32];  // per-wave [q][s], s>=16 stays zero

  const float* __restrict__ qmp = ws + QM_OFF + bh * 1024;
  const int* __restrict__ amp = (const int*)ws + AM_OFF + bh * 1024;
  const float* __restrict__ vsp = ws + VS_OFF + bh * 1024;

  // hoisted Q loads: base for this wave's q-rows; tt=0 issued NOW (latency hidden by staging)
  const float* __restrict__ qbp =
      Q + ((size_t)bh * 2048 + eighth * 256 + wv * 32 + l15) * 64 + sbase;
  f32x4 q4[2][4];
#pragma unroll
  for (int e = 0; e < 4; ++e)
    q4[0][e] = __builtin_nontemporal_load(
        (const f32x4*)(qbp + (e >> 1) * 32 + (e & 1) * 4));

  for (int i = t; i < 5760; i += 512) ((unsigned*)Gm)[i] = 0u;
  for (int i = t; i < 2048; i += 512) ((unsigned*)attn_l)[i] = 0u;
  for (int i = t; i < 1024; i += 512) Vs_l[i] = vsp[i];
  __syncthreads();
  for (int p = t; p < 1024; p += 512) {
    int s = p >> 6, dd = p & 63;
    Gm[amp[p]][s][dd] = bfb(qmp[p]);   // masked q_mean; empty clusters stay all-zero
  }
  __syncthreads();

  union Frag { unsigned u[4]; short8 s8; };

  // Vs^T A-frags (M=d, K=s padded to 32 with zeros), hoisted per wave
  Frag vf[4];
#pragma unroll
  for (int dt = 0; dt < 4; ++dt) {
#pragma unroll
    for (int e2 = 0; e2 < 4; ++e2) {
      int s0 = sbase + e2 * 2;
      float a = (s0 < 16) ? Vs_l[s0 * 64 + dt * 16 + l15] : 0.f;
      float b = (s0 + 1 < 16) ? Vs_l[(s0 + 1) * 64 + dt * 16 + l15] : 0.f;
      vf[dt].u[e2] = pk2(a, b);
    }
  }

#pragma unroll
  for (int tt = 0; tt < 2; ++tt) {
    int qbase = eighth * 256 + wv * 32 + tt * 16;
    if (tt == 0) {   // issue tt=1 loads early; latency hidden by tt=0 compute
#pragma unroll
      for (int e = 0; e < 4; ++e)
        q4[1][e] = __builtin_nontemporal_load(
            (const f32x4*)(qbp + 1024 + (e >> 1) * 32 + (e & 1) * 4));
    }

    // B-frags = Q^T from prefetched registers
    Frag bf[2];
#pragma unroll
    for (int ks = 0; ks < 2; ++ks) {
      f32x4 a = q4[tt][ks * 2];
      f32x4 b2 = q4[tt][ks * 2 + 1];
      bf[ks].u[0] = pk2(a.x, a.y);
      bf[ks].u[1] = pk2(a.z, a.w);
      bf[ks].u[2] = pk2(b2.x, b2.y);
      bf[ks].u[3] = pk2(b2.z, b2.w);
    }

    f32x4 acc[10];
#pragma unroll
    for (int c = 0; c < 10; ++c) acc[c] = (f32x4){0.f, 0.f, 0.f, 0.f};
#pragma unroll
    for (int ks = 0; ks < 2; ++ks) {
#pragma unroll
      for (int c = 0; c < 10; ++c) {
        short8 af = *(const short8*)(const void*)&Gm[c][l15][sbase + ks * 32];
        acc[c] = __builtin_amdgcn_mfma_f32_16x16x32_bf16(af, bf[ks].s8, acc[c], 0, 0, 0);
      }
    }
    // max over clusters (empty clusters contribute their all-zero tile, as in the reference)
    f32x4 fs = acc[0];
#pragma unroll
    for (int c = 1; c < 10; ++c) {
      fs.x = fmaxf(fs.x, acc[c].x); fs.y = fmaxf(fs.y, acc[c].y);
      fs.z = fmaxf(fs.z, acc[c].z); fs.w = fmaxf(fs.w, acc[c].w);
    }
    // softmax over s = row dim: reduce 4 regs + lane-groups (xor 16, 32)
    float mx = fmaxf(fmaxf(fs.x, fs.y), fmaxf(fs.z, fs.w));
    mx = fmaxf(mx, __shfl_xor(mx, 16));
    mx = fmaxf(mx, __shfl_xor(mx, 32));
    float e0 = __expf(fs.x - mx), e1 = __expf(fs.y - mx),
          e2 = __expf(fs.z - mx), e3 = __expf(fs.w - mx);
    float ssum = e0 + e1 + e2 + e3;
    ssum += __shfl_xor(ssum, 16);
    ssum += __shfl_xor(ssum, 32);
    float inv = 1.f / ssum;
    // bounce attn through wave-private LDS to reach the B-frag layout
    unsigned* awp = (unsigned*)&attn_l[wv][l15][g4];
    awp[0] = pk2(e0 * inv, e1 * inv);
    awp[1] = pk2(e2 * inv, e3 * inv);
    short8 b2f = *(const short8*)(const void*)&attn_l[wv][l15][sbase];
#pragma unroll
    for (int dt = 0; dt < 4; ++dt) {
      f32x4 ct = (f32x4){0.f, 0.f, 0.f, 0.f};
      ct = __builtin_amdgcn_mfma_f32_16x16x32_bf16(vf[dt].s8, b2f, ct, 0, 0, 0);
      float* op = out + ((size_t)bh * 2048 + qbase + l15) * 64 + dt * 16 + g4;
      __builtin_nontemporal_store(ct, (f32x4*)op);
    }
  }

  // loss = -mean(log_prob) + ce   (deterministic sum of per-block partials)
  if (bid == 0 && t == 0) {
    float Ls = 0.f, Cs = 0.f;
    for (int i = 0; i < 256; ++i) { Ls += ws[LP_OFF + i]; Cs += ws[CE_OFF + i]; }
    out[33554432] = -Ls / 2621440.f - Cs / 163840.f;
  }
}

extern "C" void kernel_launch(void* const* d_in, const int* in_sizes, int n_in,
                              void* d_out, int out_size, void* d_ws, size_t ws_size,
                              hipStream_t stream) {
  const float* Q   = (const float*)d_in[0];
  const float* K   = (const float*)d_in[1];
  const float* V   = (const float*)d_in[2];
  const float* skw = (const float*)d_in[3];
  const float* skb = (const float*)d_in[4];
  const float* svw = (const float*)d_in[5];
  const float* svb = (const float*)d_in[6];
  const float* pw  = (const float*)d_in[7];
  const float* pb  = (const float*)d_in[8];
  const float* ckw = (const float*)d_in[9];
  const float* ckb = (const float*)d_in[10];
  const float* cqw = (const float*)d_in[11];
  const float* cqb = (const float*)d_in[12];
  const float* muw = (const float*)d_in[13];
  const float* mub = (const float*)d_in[14];
  const float* sgw = (const float*)d_in[15];
  const float* sgb = (const float*)d_in[16];
  float* out = (float*)d_out;
  float* ws  = (float*)d_ws;

  hipLaunchKernelGGL(k_shrink8, dim3(512), dim3(256), 0, stream, K, V, skw, skb, svw, svb, ws);
  hipLaunchKernelGGL(k_cluster, dim3(256), dim3(1024), 0, stream,
                     pw, pb, ckw, ckb, cqw, cqb, muw, mub, sgw, sgb, ws);
  hipLaunchKernelGGL(k_attn, dim3(2048), dim3(512), 0, stream, Q, out, ws);
}